// Round 3
// baseline (277.717 us; speedup 1.0000x reference)
//
#include <hip/hip_runtime.h>
#include <hip/hip_bf16.h>

typedef __attribute__((ext_vector_type(8))) short short8;
typedef __attribute__((ext_vector_type(4))) float f32x4;
typedef __attribute__((ext_vector_type(2))) float f32x2;

#define LOG2E  1.44269504088896340736f
#define NLOG2E (-1.44269504088896340736f)
#define TLOG2E (2.88539008177792681472f)

#define HS 152          // h_bf row stride in shorts (304B: 16B-aligned, 76 dw = 12 mod 32)
#define PS 524          // ptab4 row stride in dwords (2096B: 16B-aligned, 12 mod 32)

__device__ __forceinline__ unsigned short f2bf(float f) {
  unsigned u = __builtin_bit_cast(unsigned, f);
  u += 0x7fffu + ((u >> 16) & 1u);
  return (unsigned short)(u >> 16);
}

// -------------------- merged setup: P tables + MLP weight transpose -------
__global__ void setup_kernel(
    const float* __restrict__ E_time, const float* __restrict__ E_week,
    const float* __restrict__ Wh_x, const float* __restrict__ bh,
    const float* __restrict__ Ww_x, const float* __restrict__ bw,
    const float* __restrict__ W1, const float* __restrict__ W2,
    const float* __restrict__ W3, const float* __restrict__ W4,
    float* __restrict__ Ptime, float* __restrict__ Pweek,
    unsigned short* __restrict__ Wt)
{
  const int b = blockIdx.x;
  const int tid = threadIdx.x;
  if (b < 31) {
    const int c = tid;            // 0..383
    if (b < 24) {
      float acc = bh[c];
      for (int d = 0; d < 128; ++d)
        acc = fmaf(E_time[b * 128 + d], Wh_x[d * 384 + c], acc);
      Ptime[b * 384 + c] = acc;
    } else {
      const int r = b - 24;
      float acc = bw[c];
      for (int d = 0; d < 128; ++d)
        acc = fmaf(E_week[r * 128 + d], Ww_x[d * 384 + c], acc);
      Pweek[r * 384 + c] = acc;
    }
    return;
  }
  const int id = (b - 31) * 384 + tid;
  if (id >= 819200) return;
  if (id < 131072) {                 // W1t [1024][128]
    const int n = id >> 7, k = id & 127;
    Wt[id] = f2bf(W1[k * 1024 + n]);
  } else if (id < 655360) {          // W2t [512][1024]
    const int off = id - 131072, n = off >> 10, k = off & 1023;
    Wt[id] = f2bf(W2[k * 512 + n]);
  } else if (id < 786432) {          // W3t [256][512]
    const int off = id - 655360, n = off >> 9, k = off & 511;
    Wt[id] = f2bf(W3[k * 256 + n]);
  } else {                           // W4t [128][256]
    const int off = id - 786432, n = off >> 8, k = off & 255;
    Wt[id] = f2bf(W4[k * 128 + n]);
  }
}

// -------------------- persistent GRU kernel v3 ----------------------------
// grid 192 = 3 GRUs x 64 chunks of 16 rows. 256 threads = 4 waves.
// Wave owns 6 col-tiles: gates {z,r,n} x j-halves {wv*16+ar, 64+wv*16+ar}.
// One barrier/step; h double-buffered; exp-scales folded into weights.
__global__ __launch_bounds__(256, 1) void gru_kernel(
    const float* __restrict__ spatial,
    const int* __restrict__ hour_idx,
    const int* __restrict__ week_idx,
    const float* __restrict__ Ws_x,
    const float* __restrict__ Ws_h, const float* __restrict__ bs,
    const float* __restrict__ Wh_h, const float* __restrict__ bh,
    const float* __restrict__ Ww_h, const float* __restrict__ bw,
    const float* __restrict__ Ptime, const float* __restrict__ Pweek,
    float* __restrict__ fs, float* __restrict__ fh, float* __restrict__ fw)
{
  __shared__ __align__(16) unsigned short h_bf[2][16 * HS];
  __shared__ __align__(16) float ptab4[24 * PS];           // [ix][j][4] (z,r,n,pad)
  __shared__ __align__(16) float xsp[256 * 16 * 2];        // spatial [t][i][2]
  __shared__ __align__(16) unsigned char idx8[256 * 16];   // [t][i]

  const int tid  = threadIdx.x;
  const int lane = tid & 63;
  const int wv   = tid >> 6;       // 0..3
  const int ar   = lane & 15;
  const int akg  = lane >> 4;      // 0..3
  const int gid  = blockIdx.x;
  const int gru  = gid >> 6;
  const int row0 = (gid & 63) * 16;

  const float* __restrict__ Wh   = (gru == 0) ? Ws_h : (gru == 1) ? Wh_h : Ww_h;
  const float* __restrict__ bvec = (gru == 0) ? bs   : (gru == 1) ? bh   : bw;
  float* __restrict__ fout       = (gru == 0) ? fs   : (gru == 1) ? fh   : fw;

  const int j1 = wv * 16 + ar;     // first owned col
  const int j2 = j1 + 64;          // second owned col
  const float gsc[3] = {NLOG2E, NLOG2E, TLOG2E};

  // Wh B-fragments (scaled bf16) in registers: 6 tiles x 4 ks = 96 VGPR
  short8 wfrag[3][2][4];
  #pragma unroll
  for (int g = 0; g < 3; ++g) {
    #pragma unroll
    for (int jh = 0; jh < 2; ++jh) {
      const int n = g * 128 + jh * 64 + j1;
      #pragma unroll
      for (int ks = 0; ks < 4; ++ks) {
        const int k0 = ks * 32 + akg * 8;
        short8 f;
        #pragma unroll
        for (int q = 0; q < 8; ++q)
          f[q] = (short)f2bf(Wh[(k0 + q) * 384 + n] * gsc[g]);
        wfrag[g][jh][ks] = f;
      }
    }
  }

  // b1 biases (scaled) folded into accumulator init
  float bacc[3][2];
  #pragma unroll
  for (int g = 0; g < 3; ++g) {
    bacc[g][0] = bvec[384 + g * 128 + j1] * gsc[g];
    bacc[g][1] = bvec[384 + g * 128 + j2] * gsc[g];
  }

  // spatial-GRU x weights (scaled), only gru 0
  float w0g[2][3], w1g[2][3], b0g[2][3];
  if (gru == 0) {
    #pragma unroll
    for (int jh = 0; jh < 2; ++jh) {
      const int jj = jh ? j2 : j1;
      #pragma unroll
      for (int g = 0; g < 3; ++g) {
        w0g[jh][g] = Ws_x[      g * 128 + jj] * gsc[g];
        w1g[jh][g] = Ws_x[384 + g * 128 + jj] * gsc[g];
        b0g[jh][g] = bvec[      g * 128 + jj] * gsc[g];
      }
    }
  }

  // ---- preload per-step input info ----
  if (gru == 0) {
    for (int e = tid; e < 16 * 256; e += 256) {
      const int i = e >> 8, t = e & 255;
      const f32x2 v = *(const f32x2*)&spatial[((row0 + i) * 256 + t) * 2];
      *(f32x2*)&xsp[(t * 16 + i) * 2] = v;
    }
  } else {
    const int* __restrict__ idxg = (gru == 1) ? hour_idx : week_idx;
    for (int e = tid; e < 16 * 256; e += 256) {
      const int i = e >> 8, t = e & 255;
      idx8[t * 16 + i] = (unsigned char)idxg[(row0 + i) * 256 + t];
    }
    const float* __restrict__ P = (gru == 1) ? Ptime : Pweek;
    const int nr = (gru == 1) ? 24 : 7;
    for (int e = tid; e < nr * 384; e += 256) {
      const int ix = e / 384, c = e - ix * 384;
      const int g = c >> 7, jj = c & 127;
      ptab4[ix * PS + jj * 4 + g] = P[e] * gsc[g];
    }
  }
  for (int e = tid; e < 16 * HS; e += 256) h_bf[0][e] = 0;
  __syncthreads();

  float hst[2][4];
  #pragma unroll
  for (int jh = 0; jh < 2; ++jh)
    #pragma unroll
    for (int r2 = 0; r2 < 4; ++r2) hst[jh][r2] = 0.f;

  const int abase = ar * HS;       // A-frag row base (shorts)

  auto step = [&](int t, const unsigned short* __restrict__ hb,
                  unsigned short* __restrict__ ho) {
    // ---- x-part loads first (fill LDS queue; latency hides under MFMA) ----
    float xp[4][2][3];
    if (gru == 0) {
      #pragma unroll
      for (int r2 = 0; r2 < 4; ++r2) {
        const f32x2 s = *(const f32x2*)&xsp[(t * 16 + akg * 4 + r2) * 2];
        #pragma unroll
        for (int jh = 0; jh < 2; ++jh)
          #pragma unroll
          for (int g = 0; g < 3; ++g)
            xp[r2][jh][g] = fmaf(s.y, w1g[jh][g], fmaf(s.x, w0g[jh][g], b0g[jh][g]));
      }
    } else {
      const unsigned pk = *(const unsigned*)&idx8[t * 16 + akg * 4];
      #pragma unroll
      for (int r2 = 0; r2 < 4; ++r2) {
        const int ix = (pk >> (8 * r2)) & 255;
        const f32x4 v1 = *(const f32x4*)&ptab4[ix * PS + j1 * 4];
        const f32x4 v2 = *(const f32x4*)&ptab4[ix * PS + j2 * 4];
        xp[r2][0][0] = v1.x; xp[r2][0][1] = v1.y; xp[r2][0][2] = v1.z;
        xp[r2][1][0] = v2.x; xp[r2][1][1] = v2.y; xp[r2][1][2] = v2.z;
      }
    }

    // ---- MFMA: hp = h @ Wh' (+b1'), 6 tiles in-register ----
    f32x4 acc[3][2];
    #pragma unroll
    for (int g = 0; g < 3; ++g)
      #pragma unroll
      for (int jh = 0; jh < 2; ++jh)
        acc[g][jh] = f32x4{bacc[g][jh], bacc[g][jh], bacc[g][jh], bacc[g][jh]};
    #pragma unroll
    for (int ks = 0; ks < 4; ++ks) {
      const short8 a = *(const short8*)&hb[abase + ks * 32 + akg * 8];
      #pragma unroll
      for (int g = 0; g < 3; ++g)
        #pragma unroll
        for (int jh = 0; jh < 2; ++jh)
          acc[g][jh] = __builtin_amdgcn_mfma_f32_16x16x32_bf16(a, wfrag[g][jh][ks], acc[g][jh], 0, 0, 0);
    }

    // ---- gates in-register ----
    #pragma unroll
    for (int jh = 0; jh < 2; ++jh) {
      float hn4[4];
      #pragma unroll
      for (int r2 = 0; r2 < 4; ++r2) {
        const float z  = __builtin_amdgcn_rcpf(1.f + __builtin_amdgcn_exp2f(xp[r2][jh][0] + acc[0][jh][r2]));
        const float rr = __builtin_amdgcn_rcpf(1.f + __builtin_amdgcn_exp2f(xp[r2][jh][1] + acc[1][jh][r2]));
        const float e  = __builtin_amdgcn_exp2f(fmaf(rr, acc[2][jh][r2], xp[r2][jh][2]));
        const float hh = fmaf(-2.f, __builtin_amdgcn_rcpf(e + 1.f), 1.f);
        hn4[r2] = fmaf(z, hst[jh][r2] - hh, hh);
        hst[jh][r2] = hn4[r2];
      }
      unsigned p01, p23;
      asm("v_cvt_pk_bf16_f32 %0, %1, %2" : "=v"(p01) : "v"(hn4[0]), "v"(hn4[1]));
      asm("v_cvt_pk_bf16_f32 %0, %1, %2" : "=v"(p23) : "v"(hn4[2]), "v"(hn4[3]));
      const int jj = jh ? j2 : j1;
      ho[(akg * 4 + 0) * HS + jj] = (unsigned short)(p01 & 0xffffu);
      ho[(akg * 4 + 1) * HS + jj] = (unsigned short)(p01 >> 16);
      ho[(akg * 4 + 2) * HS + jj] = (unsigned short)(p23 & 0xffffu);
      ho[(akg * 4 + 3) * HS + jj] = (unsigned short)(p23 >> 16);
    }
    __syncthreads();
  };

  for (int tt = 0; tt < 128; ++tt) {
    step(2 * tt,     h_bf[0], h_bf[1]);
    step(2 * tt + 1, h_bf[1], h_bf[0]);
  }

  #pragma unroll
  for (int jh = 0; jh < 2; ++jh) {
    const int jj = jh ? j2 : j1;
    #pragma unroll
    for (int r2 = 0; r2 < 4; ++r2)
      fout[(row0 + akg * 4 + r2) * 128 + jj] = hst[jh][r2];
  }
}

// -------------------- fused attention + MLP -------------------------------
template<int K, int N>
__device__ __forceinline__ void mlp_layer(
    const unsigned short* __restrict__ xin, unsigned short* __restrict__ xout,
    const unsigned short* __restrict__ Wt, const float* __restrict__ bias,
    int lane, int wv, float* __restrict__ foutF)
{
  constexpr int NT = N / 64;
  const int ar  = lane & 15;
  const int akg = lane >> 4;
  f32x4 acc[NT];
  #pragma unroll
  for (int nt = 0; nt < NT; ++nt) acc[nt] = f32x4{0.f, 0.f, 0.f, 0.f};
  for (int ks = 0; ks < K / 32; ++ks) {
    const short8 a = *(const short8*)&xin[ar * 1032 + ks * 32 + akg * 8];
    #pragma unroll
    for (int nt = 0; nt < NT; ++nt) {
      const int n = wv * (N / 4) + nt * 16 + ar;
      const short8 b = *(const short8*)&Wt[n * K + ks * 32 + akg * 8];
      acc[nt] = __builtin_amdgcn_mfma_f32_16x16x32_bf16(a, b, acc[nt], 0, 0, 0);
    }
  }
  const int rbase = akg * 4;
  #pragma unroll
  for (int nt = 0; nt < NT; ++nt) {
    const int n = wv * (N / 4) + nt * 16 + ar;
    const float bv = bias[n];
    #pragma unroll
    for (int q = 0; q < 4; ++q) {
      float v = acc[nt][q] + bv;
      v = fmaxf(v, 0.f);
      xout[(rbase + q) * 1032 + n] = f2bf(v);
      if (foutF) foutF[(rbase + q) * 128 + n] = v;
    }
  }
}

__global__ __launch_bounds__(256) void attn_mlp_kernel(
    const float* __restrict__ fs, const float* __restrict__ fh, const float* __restrict__ fw,
    const float* __restrict__ Wa, const float* __restrict__ ba,
    const unsigned short* __restrict__ Wt,
    const float* __restrict__ b1, const float* __restrict__ b2,
    const float* __restrict__ b3, const float* __restrict__ b4,
    const float* __restrict__ Wo, const float* __restrict__ bo,
    float* __restrict__ out)
{
  __shared__ __align__(16) unsigned short xa[16 * 1032];
  __shared__ __align__(16) unsigned short xb[16 * 1032];
  __shared__ __align__(16) float sf_l[16 * 128];
  __shared__ __align__(16) float x4f[16 * 128];

  const int tid  = threadIdx.x;
  const int lane = tid & 63;
  const int wv   = tid >> 6;
  const int row0 = blockIdx.x * 16;

  {
    const int i  = tid >> 4;
    const int j0 = (tid & 15) * 8;
    float wa[9], bav[3];
    #pragma unroll
    for (int q = 0; q < 9; ++q) wa[q] = Wa[q];
    #pragma unroll
    for (int q = 0; q < 3; ++q) bav[q] = ba[q];
    const int base = (row0 + i) * 128 + j0;
    #pragma unroll
    for (int half = 0; half < 2; ++half) {
      const f32x4 a = *(const f32x4*)&fs[base + half * 4];
      const f32x4 b = *(const f32x4*)&fh[base + half * 4];
      const f32x4 c = *(const f32x4*)&fw[base + half * 4];
      #pragma unroll
      for (int q = 0; q < 4; ++q) {
        const float f0 = a[q], f1 = b[q], f2 = c[q];
        float s0 = f0 * wa[0] + f1 * wa[3] + f2 * wa[6] + bav[0];
        float s1 = f0 * wa[1] + f1 * wa[4] + f2 * wa[7] + bav[1];
        float s2 = f0 * wa[2] + f1 * wa[5] + f2 * wa[8] + bav[2];
        s0 = fmaxf(s0, 0.f); s1 = fmaxf(s1, 0.f); s2 = fmaxf(s2, 0.f);
        const float m  = fmaxf(s0, fmaxf(s1, s2));
        const float e0 = __builtin_amdgcn_exp2f((s0 - m) * LOG2E);
        const float e1 = __builtin_amdgcn_exp2f((s1 - m) * LOG2E);
        const float e2 = __builtin_amdgcn_exp2f((s2 - m) * LOG2E);
        const float inv = __builtin_amdgcn_rcpf(e0 + e1 + e2);
        const float sf  = (f0 * e0 + f1 * e1 + f2 * e2) * inv;
        const int jj = j0 + half * 4 + q;
        sf_l[i * 128 + jj] = sf;
        xa[i * 1032 + jj]  = f2bf(sf);
      }
    }
  }
  __syncthreads();

  mlp_layer<128, 1024>(xa, xb, Wt,          b1, lane, wv, nullptr);
  __syncthreads();
  mlp_layer<1024, 512>(xb, xa, Wt + 131072, b2, lane, wv, nullptr);
  __syncthreads();
  mlp_layer<512,  256>(xa, xb, Wt + 655360, b3, lane, wv, nullptr);
  __syncthreads();
  mlp_layer<256,  128>(xb, xa, Wt + 786432, b4, lane, wv, x4f);
  __syncthreads();

  const int row = tid >> 4;
  const int p   = tid & 15;
  float part = 0.f;
  #pragma unroll
  for (int q = 0; q < 8; ++q) {
    const int jj = p + q * 16;
    part += (x4f[row * 128 + jj] + sf_l[row * 128 + jj]) * Wo[jj];
  }
  #pragma unroll
  for (int off = 8; off > 0; off >>= 1)
    part += __shfl_xor(part, off, 16);
  if (p == 0) out[row0 + row] = part + bo[0];
}

// -------------------- launch ----------------------------------------------
extern "C" void kernel_launch(void* const* d_in, const int* in_sizes, int n_in,
                              void* d_out, int out_size, void* d_ws, size_t ws_size,
                              hipStream_t stream) {
  const float* spatial  = (const float*)d_in[0];
  const int*   hour_idx = (const int*)d_in[1];
  const int*   week_idx = (const int*)d_in[2];
  const float* E_time   = (const float*)d_in[3];
  const float* E_week   = (const float*)d_in[4];
  const float* Ws_x = (const float*)d_in[5];
  const float* Ws_h = (const float*)d_in[6];
  const float* bs   = (const float*)d_in[7];
  const float* Wh_x = (const float*)d_in[8];
  const float* Wh_h = (const float*)d_in[9];
  const float* bh   = (const float*)d_in[10];
  const float* Ww_x = (const float*)d_in[11];
  const float* Ww_h = (const float*)d_in[12];
  const float* bw   = (const float*)d_in[13];
  const float* Wa   = (const float*)d_in[14];
  const float* ba   = (const float*)d_in[15];
  const float* W1   = (const float*)d_in[16];
  const float* b1   = (const float*)d_in[17];
  const float* W2   = (const float*)d_in[18];
  const float* b2   = (const float*)d_in[19];
  const float* W3   = (const float*)d_in[20];
  const float* b3   = (const float*)d_in[21];
  const float* W4   = (const float*)d_in[22];
  const float* b4   = (const float*)d_in[23];
  const float* Wo   = (const float*)d_in[24];
  const float* bo   = (const float*)d_in[25];
  float* out = (float*)d_out;

  float* ws    = (float*)d_ws;
  float* Ptime = ws;                     // 24*384
  float* Pweek = Ptime + 9216;           // 7*384
  float* fsb   = Pweek + 2688;           // 1024*128
  float* fhb   = fsb + 131072;
  float* fwb   = fhb + 131072;
  unsigned short* Wt = (unsigned short*)(fwb + 131072);  // 819200 bf16

  setup_kernel<<<31 + 2134, 384, 0, stream>>>(E_time, E_week, Wh_x, bh, Ww_x, bw,
      W1, W2, W3, W4, Ptime, Pweek, Wt);
  gru_kernel<<<192, 256, 0, stream>>>(spatial, hour_idx, week_idx, Ws_x,
      Ws_h, bs, Wh_h, bh, Ww_h, bw, Ptime, Pweek, fsb, fhb, fwb);
  attn_mlp_kernel<<<64, 256, 0, stream>>>(fsb, fhb, fwb, Wa, ba, Wt,
      b1, b2, b3, b4, Wo, bo, out);
}

// Round 4
// 240.696 us; speedup vs baseline: 1.1538x; 1.1538x over previous
//
#include <hip/hip_runtime.h>
#include <hip/hip_bf16.h>

typedef __attribute__((ext_vector_type(8))) short short8;
typedef __attribute__((ext_vector_type(4))) float f32x4;
typedef __attribute__((ext_vector_type(2))) float f32x2;

#define LOG2E  1.44269504088896340736f
#define NLOG2E (-1.44269504088896340736f)
#define TLOG2E (2.88539008177792681472f)

#define HES 168   // h_ext row stride in shorts: 84 dw == 20 mod 32 -> 2-way (free) on b128 reads

__device__ __forceinline__ unsigned short f2bf(float f) {
  unsigned u = __builtin_bit_cast(unsigned, f);
  u += 0x7fffu + ((u >> 16) & 1u);
  return (unsigned short)(u >> 16);
}

// -------------------- merged setup: P tables + MLP weight transpose -------
__global__ void setup_kernel(
    const float* __restrict__ E_time, const float* __restrict__ E_week,
    const float* __restrict__ Wh_x, const float* __restrict__ bh,
    const float* __restrict__ Ww_x, const float* __restrict__ bw,
    const float* __restrict__ W1, const float* __restrict__ W2,
    const float* __restrict__ W3, const float* __restrict__ W4,
    float* __restrict__ Ptime, float* __restrict__ Pweek,
    unsigned short* __restrict__ Wt)
{
  const int b = blockIdx.x;
  const int tid = threadIdx.x;
  if (b < 31) {
    const int c = tid;            // 0..383
    if (b < 24) {
      float acc = bh[c];
      for (int d = 0; d < 128; ++d)
        acc = fmaf(E_time[b * 128 + d], Wh_x[d * 384 + c], acc);
      Ptime[b * 384 + c] = acc;
    } else {
      const int r = b - 24;
      float acc = bw[c];
      for (int d = 0; d < 128; ++d)
        acc = fmaf(E_week[r * 128 + d], Ww_x[d * 384 + c], acc);
      Pweek[r * 384 + c] = acc;
    }
    return;
  }
  const int id = (b - 31) * 384 + tid;
  if (id >= 819200) return;
  if (id < 131072) {                 // W1t [1024][128]
    const int n = id >> 7, k = id & 127;
    Wt[id] = f2bf(W1[k * 1024 + n]);
  } else if (id < 655360) {          // W2t [512][1024]
    const int off = id - 131072, n = off >> 10, k = off & 1023;
    Wt[id] = f2bf(W2[k * 512 + n]);
  } else if (id < 786432) {          // W3t [256][512]
    const int off = id - 655360, n = off >> 9, k = off & 511;
    Wt[id] = f2bf(W3[k * 256 + n]);
  } else {                           // W4t [128][256]
    const int off = id - 786432, n = off >> 8, k = off & 255;
    Wt[id] = f2bf(W4[k * 128 + n]);
  }
}

// -------------------- persistent GRU kernel v4 ----------------------------
// grid 192 = 3 GRUs x 64 chunks of 16 rows. 512 threads = 8 waves.
// Wave wv owns cols j = wv*16+ar for gates z/r/nh/nx (4 logical tiles,
// 15 MFMA). x-projection folded into extension rows of the K dim
// (onehot(idx) @ P  or  (sx,sy) @ (w0,w1)). Gates pure-register.
__global__ __launch_bounds__(512, 2) void gru_kernel(
    const float* __restrict__ spatial,
    const int* __restrict__ hour_idx,
    const int* __restrict__ week_idx,
    const float* __restrict__ Ws_x,
    const float* __restrict__ Ws_h, const float* __restrict__ bs,
    const float* __restrict__ Wh_h, const float* __restrict__ bh,
    const float* __restrict__ Ww_h, const float* __restrict__ bw,
    const float* __restrict__ Ptime, const float* __restrict__ Pweek,
    float* __restrict__ fs, float* __restrict__ fh, float* __restrict__ fw)
{
  __shared__ __align__(16) unsigned short hx[2][16 * HES];

  const int tid  = threadIdx.x;
  const int lane = tid & 63;
  const int wv   = tid >> 6;       // 0..7
  const int ar   = lane & 15;
  const int akg  = lane >> 4;      // 0..3
  const int gid  = blockIdx.x;
  const int gru  = gid >> 6;
  const int row0 = (gid & 63) * 16;

  const float* __restrict__ Wh   = (gru == 0) ? Ws_h : (gru == 1) ? Wh_h : Ww_h;
  const float* __restrict__ bvec = (gru == 0) ? bs   : (gru == 1) ? bh   : bw;
  float* __restrict__ fout       = (gru == 0) ? fs   : (gru == 1) ? fh   : fw;
  const float* __restrict__ Ptab = (gru == 1) ? Ptime : Pweek;
  const int* __restrict__ idxg   = (gru == 1) ? hour_idx : week_idx;
  const int NR = (gru == 1) ? 24 : 7;

  const int j = wv * 16 + ar;      // owned hidden col

  // ---- weight fragments: wf[0..4]=z(ks0..4), wf[5..9]=r, wf[10..13]=nh, wf[14]=nx
  short8 wf[15];
  #pragma unroll
  for (int g = 0; g < 2; ++g) {
    #pragma unroll
    for (int ks = 0; ks < 5; ++ks) {
      short8 f;
      #pragma unroll
      for (int q = 0; q < 8; ++q) {
        const int k = ks * 32 + akg * 8 + q;
        float v;
        if (k < 128) v = Wh[k * 384 + g * 128 + j];
        else {
          const int p = k - 128;
          if (gru == 0) v = (p == 0) ? Ws_x[g * 128 + j]
                          : (p == 1) ? Ws_x[384 + g * 128 + j] : 0.f;
          else          v = (p < NR) ? Ptab[p * 384 + g * 128 + j] : 0.f;
        }
        f[q] = (short)f2bf(v * NLOG2E);
      }
      wf[g * 5 + ks] = f;
    }
  }
  #pragma unroll
  for (int ks = 0; ks < 4; ++ks) {   // nh (h-side only, K=128)
    short8 f;
    #pragma unroll
    for (int q = 0; q < 8; ++q) {
      const int k = ks * 32 + akg * 8 + q;
      f[q] = (short)f2bf(Wh[k * 384 + 256 + j] * TLOG2E);
    }
    wf[10 + ks] = f;
  }
  {                                  // nx (extension rows only)
    short8 f;
    #pragma unroll
    for (int q = 0; q < 8; ++q) {
      const int p = akg * 8 + q;
      float v;
      if (gru == 0) v = (p == 0) ? Ws_x[256 + j]
                      : (p == 1) ? Ws_x[384 + 256 + j] : 0.f;
      else          v = (p < NR) ? Ptab[p * 384 + 256 + j] : 0.f;
      f[q] = (short)f2bf(v * TLOG2E);
    }
    wf[14] = f;
  }

  // exact fp32 biases in accumulator init (b0 for gru1/2 lives inside P)
  const float bz  = (bvec[384 + j]       + (gru == 0 ? bvec[j]       : 0.f)) * NLOG2E;
  const float br  = (bvec[384 + 128 + j] + (gru == 0 ? bvec[128 + j] : 0.f)) * NLOG2E;
  const float bnh = bvec[384 + 256 + j] * TLOG2E;
  const float bnx = (gru == 0 ? bvec[256 + j] : 0.f) * TLOG2E;

  // ---- zero both h_ext buffers, then place step-0 extension values ----
  for (int e = tid; e < 2 * 16 * HES; e += 512) ((unsigned short*)hx)[e] = 0;
  __syncthreads();

  const bool mt  = (tid & 31) == 0;  // 16 maintenance threads, 2 per wave
  const int mrow = tid >> 5;
  int ix_prev = 0, ix_cur = 0;
  if (mt) {
    if (gru == 0) {
      const f32x2 s = *(const f32x2*)&spatial[(row0 + mrow) * 512];
      unsigned pk;
      asm("v_cvt_pk_bf16_f32 %0, %1, %2" : "=v"(pk) : "v"(s.x), "v"(s.y));
      *(unsigned*)&hx[0][mrow * HES + 128] = pk;
    } else {
      ix_cur = idxg[(row0 + mrow) * 256];
      hx[0][mrow * HES + 128 + ix_cur] = 0x3F80;   // bf16 1.0
    }
  }
  __syncthreads();

  float hst[4] = {0.f, 0.f, 0.f, 0.f};

  for (int t = 0; t < 256; ++t) {
    const unsigned short* __restrict__ hb = hx[t & 1];
    unsigned short* __restrict__ ho       = hx[(t + 1) & 1];

    // ---- A-fragments FIRST (MFMA-critical; nothing ahead in the LDS queue)
    short8 a[5];
    #pragma unroll
    for (int ks = 0; ks < 5; ++ks)
      a[ks] = *(const short8*)&hb[ar * HES + ks * 32 + akg * 8];

    // ---- maintenance global prefetch for t+1 (vmcnt queue, overlaps MFMA)
    f32x2 msp = {0.f, 0.f};
    int ix_next = 0;
    const bool mact = mt && (t + 1 < 256);
    if (mact) {
      if (gru == 0) msp = *(const f32x2*)&spatial[(row0 + mrow) * 512 + 2 * (t + 1)];
      else          ix_next = idxg[(row0 + mrow) * 256 + t + 1];
    }

    // ---- MFMA: complete pre-activations (x-part via extension rows) ----
    f32x4 az  = {bz, bz, bz, bz};
    f32x4 arr = {br, br, br, br};
    f32x4 anh = {bnh, bnh, bnh, bnh};
    f32x4 anx = {bnx, bnx, bnx, bnx};
    #pragma unroll
    for (int ks = 0; ks < 4; ++ks) {
      az  = __builtin_amdgcn_mfma_f32_16x16x32_bf16(a[ks], wf[ks],      az,  0, 0, 0);
      arr = __builtin_amdgcn_mfma_f32_16x16x32_bf16(a[ks], wf[5 + ks],  arr, 0, 0, 0);
      anh = __builtin_amdgcn_mfma_f32_16x16x32_bf16(a[ks], wf[10 + ks], anh, 0, 0, 0);
    }
    az  = __builtin_amdgcn_mfma_f32_16x16x32_bf16(a[4], wf[4],  az,  0, 0, 0);
    arr = __builtin_amdgcn_mfma_f32_16x16x32_bf16(a[4], wf[9],  arr, 0, 0, 0);
    anx = __builtin_amdgcn_mfma_f32_16x16x32_bf16(a[4], wf[14], anx, 0, 0, 0);

    // ---- maintenance: write extension values for t+1 into target buffer
    if (mact) {
      if (gru == 0) {
        unsigned pk;
        asm("v_cvt_pk_bf16_f32 %0, %1, %2" : "=v"(pk) : "v"(msp.x), "v"(msp.y));
        *(unsigned*)&ho[mrow * HES + 128] = pk;
      } else {
        if (t >= 1) ho[mrow * HES + 128 + ix_prev] = 0;       // clear onehot(t-1)
        ho[mrow * HES + 128 + ix_next] = 0x3F80;              // set onehot(t+1)
        ix_prev = ix_cur; ix_cur = ix_next;
      }
    }

    // ---- gates: pure-register ----
    float hn4[4];
    #pragma unroll
    for (int q = 0; q < 4; ++q) {
      const float z  = __builtin_amdgcn_rcpf(1.f + __builtin_amdgcn_exp2f(az[q]));
      const float r  = __builtin_amdgcn_rcpf(1.f + __builtin_amdgcn_exp2f(arr[q]));
      const float e  = __builtin_amdgcn_exp2f(fmaf(r, anh[q], anx[q]));
      const float hh = fmaf(-2.f, __builtin_amdgcn_rcpf(e + 1.f), 1.f);
      hn4[q] = fmaf(z, hst[q] - hh, hh);
      hst[q] = hn4[q];
    }

    // ---- write h(t+1) ----
    #pragma unroll
    for (int q = 0; q < 4; ++q)
      ho[(akg * 4 + q) * HES + j] = f2bf(hn4[q]);

    __syncthreads();
  }

  #pragma unroll
  for (int q = 0; q < 4; ++q)
    fout[(row0 + akg * 4 + q) * 128 + j] = hst[q];
}

// -------------------- fused attention + MLP -------------------------------
template<int K, int N>
__device__ __forceinline__ void mlp_layer(
    const unsigned short* __restrict__ xin, unsigned short* __restrict__ xout,
    const unsigned short* __restrict__ Wt, const float* __restrict__ bias,
    int lane, int wv, float* __restrict__ foutF)
{
  constexpr int NT = N / 64;
  const int ar  = lane & 15;
  const int akg = lane >> 4;
  f32x4 acc[NT];
  #pragma unroll
  for (int nt = 0; nt < NT; ++nt) acc[nt] = f32x4{0.f, 0.f, 0.f, 0.f};
  for (int ks = 0; ks < K / 32; ++ks) {
    const short8 a = *(const short8*)&xin[ar * 1032 + ks * 32 + akg * 8];
    #pragma unroll
    for (int nt = 0; nt < NT; ++nt) {
      const int n = wv * (N / 4) + nt * 16 + ar;
      const short8 b = *(const short8*)&Wt[n * K + ks * 32 + akg * 8];
      acc[nt] = __builtin_amdgcn_mfma_f32_16x16x32_bf16(a, b, acc[nt], 0, 0, 0);
    }
  }
  const int rbase = akg * 4;
  #pragma unroll
  for (int nt = 0; nt < NT; ++nt) {
    const int n = wv * (N / 4) + nt * 16 + ar;
    const float bv = bias[n];
    #pragma unroll
    for (int q = 0; q < 4; ++q) {
      float v = acc[nt][q] + bv;
      v = fmaxf(v, 0.f);
      xout[(rbase + q) * 1032 + n] = f2bf(v);
      if (foutF) foutF[(rbase + q) * 128 + n] = v;
    }
  }
}

__global__ __launch_bounds__(256) void attn_mlp_kernel(
    const float* __restrict__ fs, const float* __restrict__ fh, const float* __restrict__ fw,
    const float* __restrict__ Wa, const float* __restrict__ ba,
    const unsigned short* __restrict__ Wt,
    const float* __restrict__ b1, const float* __restrict__ b2,
    const float* __restrict__ b3, const float* __restrict__ b4,
    const float* __restrict__ Wo, const float* __restrict__ bo,
    float* __restrict__ out)
{
  __shared__ __align__(16) unsigned short xa[16 * 1032];
  __shared__ __align__(16) unsigned short xb[16 * 1032];
  __shared__ __align__(16) float sf_l[16 * 128];
  __shared__ __align__(16) float x4f[16 * 128];

  const int tid  = threadIdx.x;
  const int lane = tid & 63;
  const int wv   = tid >> 6;
  const int row0 = blockIdx.x * 16;

  {
    const int i  = tid >> 4;
    const int j0 = (tid & 15) * 8;
    float wa[9], bav[3];
    #pragma unroll
    for (int q = 0; q < 9; ++q) wa[q] = Wa[q];
    #pragma unroll
    for (int q = 0; q < 3; ++q) bav[q] = ba[q];
    const int base = (row0 + i) * 128 + j0;
    #pragma unroll
    for (int half = 0; half < 2; ++half) {
      const f32x4 a = *(const f32x4*)&fs[base + half * 4];
      const f32x4 b = *(const f32x4*)&fh[base + half * 4];
      const f32x4 c = *(const f32x4*)&fw[base + half * 4];
      #pragma unroll
      for (int q = 0; q < 4; ++q) {
        const float f0 = a[q], f1 = b[q], f2 = c[q];
        float s0 = f0 * wa[0] + f1 * wa[3] + f2 * wa[6] + bav[0];
        float s1 = f0 * wa[1] + f1 * wa[4] + f2 * wa[7] + bav[1];
        float s2 = f0 * wa[2] + f1 * wa[5] + f2 * wa[8] + bav[2];
        s0 = fmaxf(s0, 0.f); s1 = fmaxf(s1, 0.f); s2 = fmaxf(s2, 0.f);
        const float m  = fmaxf(s0, fmaxf(s1, s2));
        const float e0 = __builtin_amdgcn_exp2f((s0 - m) * LOG2E);
        const float e1 = __builtin_amdgcn_exp2f((s1 - m) * LOG2E);
        const float e2 = __builtin_amdgcn_exp2f((s2 - m) * LOG2E);
        const float inv = __builtin_amdgcn_rcpf(e0 + e1 + e2);
        const float sf  = (f0 * e0 + f1 * e1 + f2 * e2) * inv;
        const int jj = j0 + half * 4 + q;
        sf_l[i * 128 + jj] = sf;
        xa[i * 1032 + jj]  = f2bf(sf);
      }
    }
  }
  __syncthreads();

  mlp_layer<128, 1024>(xa, xb, Wt,          b1, lane, wv, nullptr);
  __syncthreads();
  mlp_layer<1024, 512>(xb, xa, Wt + 131072, b2, lane, wv, nullptr);
  __syncthreads();
  mlp_layer<512,  256>(xa, xb, Wt + 655360, b3, lane, wv, nullptr);
  __syncthreads();
  mlp_layer<256,  128>(xb, xa, Wt + 786432, b4, lane, wv, x4f);
  __syncthreads();

  const int row = tid >> 4;
  const int p   = tid & 15;
  float part = 0.f;
  #pragma unroll
  for (int q = 0; q < 8; ++q) {
    const int jj = p + q * 16;
    part += (x4f[row * 128 + jj] + sf_l[row * 128 + jj]) * Wo[jj];
  }
  #pragma unroll
  for (int off = 8; off > 0; off >>= 1)
    part += __shfl_xor(part, off, 16);
  if (p == 0) out[row0 + row] = part + bo[0];
}

// -------------------- launch ----------------------------------------------
extern "C" void kernel_launch(void* const* d_in, const int* in_sizes, int n_in,
                              void* d_out, int out_size, void* d_ws, size_t ws_size,
                              hipStream_t stream) {
  const float* spatial  = (const float*)d_in[0];
  const int*   hour_idx = (const int*)d_in[1];
  const int*   week_idx = (const int*)d_in[2];
  const float* E_time   = (const float*)d_in[3];
  const float* E_week   = (const float*)d_in[4];
  const float* Ws_x = (const float*)d_in[5];
  const float* Ws_h = (const float*)d_in[6];
  const float* bs   = (const float*)d_in[7];
  const float* Wh_x = (const float*)d_in[8];
  const float* Wh_h = (const float*)d_in[9];
  const float* bh   = (const float*)d_in[10];
  const float* Ww_x = (const float*)d_in[11];
  const float* Ww_h = (const float*)d_in[12];
  const float* bw   = (const float*)d_in[13];
  const float* Wa   = (const float*)d_in[14];
  const float* ba   = (const float*)d_in[15];
  const float* W1   = (const float*)d_in[16];
  const float* b1   = (const float*)d_in[17];
  const float* W2   = (const float*)d_in[18];
  const float* b2   = (const float*)d_in[19];
  const float* W3   = (const float*)d_in[20];
  const float* b3   = (const float*)d_in[21];
  const float* W4   = (const float*)d_in[22];
  const float* b4   = (const float*)d_in[23];
  const float* Wo   = (const float*)d_in[24];
  const float* bo   = (const float*)d_in[25];
  float* out = (float*)d_out;

  float* ws    = (float*)d_ws;
  float* Ptime = ws;                     // 24*384
  float* Pweek = Ptime + 9216;           // 7*384
  float* fsb   = Pweek + 2688;           // 1024*128
  float* fhb   = fsb + 131072;
  float* fwb   = fhb + 131072;
  unsigned short* Wt = (unsigned short*)(fwb + 131072);  // 819200 bf16

  setup_kernel<<<31 + 2134, 384, 0, stream>>>(E_time, E_week, Wh_x, bh, Ww_x, bw,
      W1, W2, W3, W4, Ptime, Pweek, Wt);
  gru_kernel<<<192, 512, 0, stream>>>(spatial, hour_idx, week_idx, Ws_x,
      Ws_h, bs, Wh_h, bh, Ww_h, bw, Ptime, Pweek, fsb, fhb, fwb);
  attn_mlp_kernel<<<64, 256, 0, stream>>>(fsb, fhb, fwb, Wa, ba, Wt,
      b1, b2, b3, b4, Wo, bo, out);
}